// Round 8
// baseline (1283.940 us; speedup 1.0000x reference)
//
#include <hip/hip_runtime.h>

// BinarizedLinear: act[d,o] = sum_i W[d,o,i] * x[d,i];  out[d,o] = act > bias[d,o]
// W: [D][OUT][IN] fp32 of 0/1   (1.074 GB -- the whole cost; read once, coalesced, nontemporal)
// x: [D][IN] bool               (byte / int32 / float32 storage -- detected on device)
// bias: [D][OUT] fp32
// out: [D][OUT] as float 1.0/0.0 (reference returns bool)
//
// Persistent pipelined structure: 2048 blocks x 4 waves; each wave owns 16
// contiguous rows (single direction d -> x gates computed once, reused 16x).
// Double-buffered W registers (wA/wB, statically indexed): row k+2's 8 KB of
// nontemporal dwordx4 loads are in flight while row k is reduced. Sums are
// exact small integers in fp32, so reduction order is bit-exact vs reference.

#define NDIR 64
#define NOUT 2048
#define NIN  2048
#define ROWS_PER_WAVE 16
#define NBLOCKS ((NDIR * NOUT) / ROWS_PER_WAVE / 4)   // 2048

typedef float f4 __attribute__((ext_vector_type(4)));

#define LOADW(buf, r) do {                                                  \
    const f4* p_ = wbase + (size_t)(r) * (NIN / 4);                         \
    _Pragma("unroll")                                                       \
    for (int j = 0; j < 8; ++j)                                             \
        buf[j] = __builtin_nontemporal_load(&p_[j * 64 + lane]);            \
  } while (0)

#define COMPUTE(buf, r) do {                                                \
    float acc_ = 0.0f;                                                      \
    _Pragma("unroll")                                                       \
    for (int j = 0; j < 8; ++j) {                                           \
        acc_ += (g[j] & 1u) ? buf[j].x : 0.0f;                              \
        acc_ += (g[j] & 2u) ? buf[j].y : 0.0f;                              \
        acc_ += (g[j] & 4u) ? buf[j].z : 0.0f;                              \
        acc_ += (g[j] & 8u) ? buf[j].w : 0.0f;                              \
    }                                                                       \
    _Pragma("unroll")                                                       \
    for (int off_ = 32; off_ > 0; off_ >>= 1)                               \
        acc_ += __shfl_down(acc_, off_, 64);                                \
    if (lane == 0) {                                                        \
        const int rr_ = row0 + (r);                                         \
        out[rr_] = (acc_ > B[rr_]) ? 1.0f : 0.0f;                           \
    }                                                                       \
  } while (0)

__global__ __launch_bounds__(256) void binlin_kernel(
    const float* __restrict__ W,
    const unsigned char* __restrict__ X,
    const float* __restrict__ B,
    float* __restrict__ out)
{
    const int lane = threadIdx.x & 63;
    const int wave = threadIdx.x >> 6;
    const int wgid = blockIdx.x * 4 + wave;            // [0, 8192)
    const int row0 = wgid * ROWS_PER_WAVE;             // 16 contiguous rows
    const int d    = row0 >> 11;                       // constant per wave (16 | 2048)

    // --- storage-format probe for X (deterministic, wave-uniform) ---
    // float32: some word == 0x3F800000 (absent w.p. 2^-64).
    // bool bytes: some word > 1 (absent w.p. 8^-64).  int32: all words in {0,1}.
    const unsigned int probe = ((const unsigned int*)X)[lane];   // 256 B, in-bounds in all layouts
    const bool x_is_float = (__ballot(probe == 0x3F800000u) != 0ull);
    const bool x_is_bytes = !x_is_float && (__ballot(probe > 1u) != 0ull);

    // Per-lane gate nibbles, computed ONCE (d fixed for all 16 rows; x is L2-hot).
    unsigned int g[8];
    if (x_is_float) {
        const f4* xf = (const f4*)X + (size_t)d * (NIN / 4);
        #pragma unroll
        for (int j = 0; j < 8; ++j) {
            const f4 xv = xf[j * 64 + lane];
            g[j] = (unsigned)(xv.x != 0.0f)        | ((unsigned)(xv.y != 0.0f) << 1)
                 | ((unsigned)(xv.z != 0.0f) << 2) | ((unsigned)(xv.w != 0.0f) << 3);
        }
    } else if (x_is_bytes) {
        const unsigned int* x4 = (const unsigned int*)(X + (size_t)d * NIN);
        #pragma unroll
        for (int j = 0; j < 8; ++j) {
            const unsigned int xb = x4[j * 64 + lane];
            g[j] = ((xb & 0x000000ffu) ? 1u : 0u) | ((xb & 0x0000ff00u) ? 2u : 0u)
                 | ((xb & 0x00ff0000u) ? 4u : 0u) | ((xb & 0xff000000u) ? 8u : 0u);
        }
    } else {
        const int* xi = (const int*)X + (size_t)d * NIN;
        #pragma unroll
        for (int j = 0; j < 8; ++j) {
            const int i4 = (j * 64 + lane) * 4;
            g[j] = (xi[i4+0] ? 1u : 0u) | (xi[i4+1] ? 2u : 0u)
                 | (xi[i4+2] ? 4u : 0u) | (xi[i4+3] ? 8u : 0u);
        }
    }

    const f4* wbase = (const f4*)(W + (size_t)row0 * NIN);

    // Software pipeline over 16 rows, 2-deep register double-buffer.
    f4 wA[8], wB[8];
    LOADW(wA, 0);
    LOADW(wB, 1);
    #pragma unroll
    for (int k = 0; k < ROWS_PER_WAVE - 2; k += 2) {
        COMPUTE(wA, k);     LOADW(wA, k + 2);
        COMPUTE(wB, k + 1); LOADW(wB, k + 3);
    }
    COMPUTE(wA, ROWS_PER_WAVE - 2);
    COMPUTE(wB, ROWS_PER_WAVE - 1);
}

extern "C" void kernel_launch(void* const* d_in, const int* in_sizes, int n_in,
                              void* d_out, int out_size, void* d_ws, size_t ws_size,
                              hipStream_t stream) {
    const float*         W = (const float*)d_in[0];
    const unsigned char* X = (const unsigned char*)d_in[1];
    const float*         B = (const float*)d_in[2];
    float*               O = (float*)d_out;

    binlin_kernel<<<dim3(NBLOCKS), dim3(256), 0, stream>>>(W, X, B, O);
}